// Round 1
// 236.474 us; speedup vs baseline: 1.1481x; 1.1481x over previous
//
#include <hip/hip_runtime.h>
#include <hip/hip_fp16.h>

#define N_NODES 50000
#define N_EDGES 1600000
#define IN_DIM 256
#define OUT_DIM 128
#define NEG_SLOPE 0.01f

#define RB    32                         // rows per bucket
#define NBUCK ((N_NODES + RB - 1) / RB)  // 1563 buckets
#define CAP   1536                       // max records/bucket (mean 1024, sd 32)

#define HIST_BLOCKS 256
#define CONVW_BLOCKS 16                  // extra blocks: W fp32 -> f16 frag layout
#define EPB_H (N_EDGES / HIST_BLOCKS)    // 6250
#define SCAT_BLOCKS 512
#define EPB_S (N_EDGES / SCAT_BLOCKS)    // 3125
#define SCAT_ITERS ((EPB_S + 255) / 256) // 13

typedef _Float16 f16x8 __attribute__((ext_vector_type(8)));
typedef float    f32x4 __attribute__((ext_vector_type(4)));

// ---------------------------------------------------------------------------
// Kernel 1: h = x @ W via v_mfma_f32_16x16x32_f16 (f16 inputs, fp32 accum).
// Orientation: D[n][m] = WT[n][k] * xT[k][m]  (A = WT, B = x row-major).
//   A frag: lane l elem j = WT[n = l&15][k = 8*(l>>4)+j]   -> wt8[kgi][n]
//   B frag: lane l elem j = x[m = l&15][k = 8*(l>>4)+j]    -> xs8[kg][m]
//   D:      n = 4*(l>>4)+r (+16*nf), m = l&15 (+16*mf+32*wv) -> 8B h stores
// LDS: wt8 64 KB (whole W, frag-native, staged once from pre-converted WTL)
//      xs8 2x8 KB double-buffered K-steps. 80 KB total -> 2 blocks/CU.
// Both frag reads are ds_read_b128 at 16B row stride -> 2-way alias (free).
// Memory-bound by design: 51.2 MB x-read dominates; MFMA floor ~1.6 us.
// ---------------------------------------------------------------------------
#define BM 128
#define GEMM_BLOCKS ((N_NODES + BM - 1) / BM)   // 391

#define CVT16(lo, hi) do { \
    lo[0]=(_Float16)xr[0].x; lo[1]=(_Float16)xr[0].y; lo[2]=(_Float16)xr[0].z; lo[3]=(_Float16)xr[0].w; \
    lo[4]=(_Float16)xr[1].x; lo[5]=(_Float16)xr[1].y; lo[6]=(_Float16)xr[1].z; lo[7]=(_Float16)xr[1].w; \
    hi[0]=(_Float16)xr[2].x; hi[1]=(_Float16)xr[2].y; hi[2]=(_Float16)xr[2].z; hi[3]=(_Float16)xr[2].w; \
    hi[4]=(_Float16)xr[3].x; hi[5]=(_Float16)xr[3].y; hi[6]=(_Float16)xr[3].z; hi[7]=(_Float16)xr[3].w; \
} while (0)

__global__ __launch_bounds__(256, 2) void gemm_xw_mfma(const float* __restrict__ x,
                                                       const __half* __restrict__ wtl,
                                                       __half* __restrict__ h) {
    __shared__ f16x8 wt8[32 * 128];   // [kgi=k/8][n] -> 8 halves k..k+7 : 64 KB
    __shared__ f16x8 xs8[2][4][BM];   // [buf][kg][m] -> 8 halves         : 16 KB

    const int t    = threadIdx.x;
    const int lane = t & 63;
    const int wv   = t >> 6;          // wave 0..3
    const int row0 = blockIdx.x * BM;

    // ---- stage whole W (frag-native layout, L2-hot): linear 64 KB copy ----
    {
        const int4* src = (const int4*)wtl;
        int4* dst = (int4*)wt8;
#pragma unroll
        for (int i = 0; i < 16; ++i) dst[i * 256 + t] = src[i * 256 + t];
    }

    // ---- x staging: thread owns (row srow, k-half skh) of each K-step ----
    const int srow = t >> 1;          // 0..127
    const int skh  = t & 1;           // 0: k 0..15, 1: k 16..31 of step
    const int grow = row0 + srow;
    const bool rv  = grow < N_NODES;
    const float* xp = x + (size_t)(rv ? grow : 0) * IN_DIM + skh * 16;

    float4 xr[4];
#pragma unroll
    for (int i = 0; i < 4; ++i)
        xr[i] = rv ? ((const float4*)xp)[i] : make_float4(0.f, 0.f, 0.f, 0.f);
    {
        f16x8 lo, hi;
        CVT16(lo, hi);
        xs8[0][skh * 2 + 0][srow] = lo;
        xs8[0][skh * 2 + 1][srow] = hi;
    }
    __syncthreads();

    f32x4 acc[2][8];
#pragma unroll
    for (int mf = 0; mf < 2; ++mf)
#pragma unroll
        for (int nf = 0; nf < 8; ++nf) acc[mf][nf] = (f32x4){0.f, 0.f, 0.f, 0.f};

    const int kg  = lane >> 4;
    const int l15 = lane & 15;
    const int mb  = (wv << 5) + l15;  // this wave's base row within tile

#pragma unroll
    for (int ks = 0; ks < 8; ++ks) {
        const int cur = ks & 1;
        if (ks < 7) {                 // prefetch next K-step to regs (overlaps MFMA)
#pragma unroll
            for (int i = 0; i < 4; ++i)
                xr[i] = rv ? ((const float4*)(xp + (ks + 1) * 32))[i]
                           : make_float4(0.f, 0.f, 0.f, 0.f);
        }
        const f16x8 b0 = xs8[cur][kg][mb];
        const f16x8 b1 = xs8[cur][kg][mb + 16];
#pragma unroll
        for (int nf = 0; nf < 8; ++nf) {
            const f16x8 a = wt8[(((ks << 2) | kg) << 7) + (nf << 4) + l15];
            acc[0][nf] = __builtin_amdgcn_mfma_f32_16x16x32_f16(a, b0, acc[0][nf], 0, 0, 0);
            acc[1][nf] = __builtin_amdgcn_mfma_f32_16x16x32_f16(a, b1, acc[1][nf], 0, 0, 0);
        }
        if (ks < 7) {
            f16x8 lo, hi;
            CVT16(lo, hi);
            xs8[cur ^ 1][skh * 2 + 0][srow] = lo;
            xs8[cur ^ 1][skh * 2 + 1][srow] = hi;
            __syncthreads();          // one barrier per K-step
        }
    }

    // ---- epilogue: 4 consecutive n per lane -> 8B stores ----
    const int rg = lane >> 4;
#pragma unroll
    for (int mf = 0; mf < 2; ++mf) {
        const int m = row0 + (wv << 5) + (mf << 4) + l15;
        if (m < N_NODES) {
            __half* hp = h + (size_t)m * OUT_DIM + (rg << 2);
#pragma unroll
            for (int nf = 0; nf < 8; ++nf) {
                union { ushort4 u; __half f[4]; } o;
                o.f[0] = __float2half(acc[mf][nf][0]);
                o.f[1] = __float2half(acc[mf][nf][1]);
                o.f[2] = __float2half(acc[mf][nf][2]);
                o.f[3] = __float2half(acc[mf][nf][3]);
                *(ushort4*)(hp + (nf << 4)) = o.u;
            }
        }
    }
}

// ---------------------------------------------------------------------------
// Kernel 2: per-bucket histogram (blocks 0..255) + W fp32 -> f16 frag-layout
// transform (blocks 256..271, hides under the histogram; must precede gemm).
// WTL[kgi][n][j] = (f16) W[kgi*8+j][n]  -- the exact A-frag order.
// ---------------------------------------------------------------------------
__global__ __launch_bounds__(256) void bucket_hist(const int* __restrict__ rows,
                                                   int* __restrict__ counts,
                                                   const float* __restrict__ w,
                                                   __half* __restrict__ wtl) {
    if (blockIdx.x >= HIST_BLOCKS) {
        const int e0 = ((blockIdx.x - HIST_BLOCKS) * 256 + threadIdx.x) * 8;
        const int k  = e0 >> 7;           // one W row per thread-chunk
        const int n0 = e0 & 127;
        const float4 a = *(const float4*)(w + e0);
        const float4 b = *(const float4*)(w + e0 + 4);
        __half* dst = wtl + ((size_t)((k >> 3) * 128 + n0)) * 8 + (k & 7);
        dst[0]  = __float2half(a.x);
        dst[8]  = __float2half(a.y);
        dst[16] = __float2half(a.z);
        dst[24] = __float2half(a.w);
        dst[32] = __float2half(b.x);
        dst[40] = __float2half(b.y);
        dst[48] = __float2half(b.z);
        dst[56] = __float2half(b.w);
        return;
    }

    __shared__ int lhist[NBUCK];
    const int t = threadIdx.x;
    const int ebase = blockIdx.x * EPB_H;

    for (int b = t; b < NBUCK; b += 256) lhist[b] = 0;
    __syncthreads();

    for (int k = 0; k < EPB_H; k += 256) {
        if (k + t < EPB_H) atomicAdd(&lhist[rows[ebase + k + t] / RB], 1);
    }
    __syncthreads();

    for (int b = t; b < NBUCK; b += 256) {
        const int c = lhist[b];
        if (c > 0) atomicAdd(&counts[b], c);
    }
}

// ---------------------------------------------------------------------------
// Kernel 3: exclusive scan of 1563 bucket counts -> offsets[1564] + cursor.
// ---------------------------------------------------------------------------
__global__ __launch_bounds__(1024) void scan_buckets(const int* __restrict__ counts,
                                                     int* __restrict__ offsets,
                                                     int* __restrict__ cursor) {
    __shared__ int s[1024];
    const int t = threadIdx.x;
    const int i0 = 2 * t, i1 = 2 * t + 1;
    const int v0 = (i0 < NBUCK) ? counts[i0] : 0;
    const int v1 = (i1 < NBUCK) ? counts[i1] : 0;
    s[t] = v0 + v1;
    __syncthreads();
    for (int off = 1; off < 1024; off <<= 1) {
        int u = (t >= off) ? s[t - off] : 0;
        __syncthreads();
        s[t] += u;
        __syncthreads();
    }
    const int excl = s[t] - (v0 + v1);
    if (i0 < NBUCK) { offsets[i0] = excl;      cursor[i0] = excl; }
    if (i1 < NBUCK) { offsets[i1] = excl + v0; cursor[i1] = excl + v0; }
    if (t == 1023) offsets[NBUCK] = s[t];
}

// ---------------------------------------------------------------------------
// Kernel 4: bucket scatter. 512 blocks (2/CU) for latency hiding; row
// indices register-cached between passes (single rows[] read). Per block:
// LDS hist -> reserve contiguous per-bucket ranges -> write packed 8B
// records { col | (row%RB)<<16 , val } grouped by bucket.
// ---------------------------------------------------------------------------
__global__ __launch_bounds__(256) void bucket_scatter(const int* __restrict__ rows,
                                                      const int* __restrict__ cols,
                                                      const float* __restrict__ vals,
                                                      int* __restrict__ cursor,
                                                      int2* __restrict__ ebuf) {
    __shared__ int lcur[NBUCK];
    const int t = threadIdx.x;
    const int ebase = blockIdx.x * EPB_S;

    for (int b = t; b < NBUCK; b += 256) lcur[b] = 0;
    __syncthreads();

    int myr[SCAT_ITERS];
#pragma unroll
    for (int k = 0; k < SCAT_ITERS; ++k) {
        const int i = k * 256 + t;
        myr[k] = -1;
        if (i < EPB_S) {
            const int r = rows[ebase + i];
            myr[k] = r;
            atomicAdd(&lcur[r / RB], 1);
        }
    }
    __syncthreads();

    for (int b = t; b < NBUCK; b += 256) {
        const int c = lcur[b];
        lcur[b] = (c > 0) ? atomicAdd(&cursor[b], c) : 0;
    }
    __syncthreads();

#pragma unroll
    for (int k = 0; k < SCAT_ITERS; ++k) {
        const int i = k * 256 + t;
        if (i < EPB_S) {
            const int e = ebase + i;
            const int r = myr[k];
            const int pos = atomicAdd(&lcur[r / RB], 1);
            ebuf[pos] = make_int2(cols[e] | ((r & (RB - 1)) << 16), __float_as_int(vals[e]));
        }
    }
}

// ---------------------------------------------------------------------------
// Kernel 5: bucket gather — two-pass counting sort from L2-hot ebuf (pass 1:
// per-row LDS histogram; pass 2: sort into ~12.3 KB LDS), then pure register
// accumulation over fp16 h. Fused leaky-ReLU, out written exactly once.
// No fp atomics, no per-row global atomics.
// ---------------------------------------------------------------------------
__global__ __launch_bounds__(256) void bucket_gather(const __half* __restrict__ h,
                                                     const int* __restrict__ offsets,
                                                     const int2* __restrict__ ebuf,
                                                     float* __restrict__ out) {
    __shared__ int2 srec[CAP];      // 12.3 KB sorted-by-row records
    __shared__ int  hist[RB];       // per-row count -> sort cursor
    __shared__ int  rowoff[RB + 1];

    const int t    = threadIdx.x;
    const int bkt  = blockIdx.x;
    const int wave = t >> 6;
    const int lane = t & 63;

    const int base = offsets[bkt];
    const int cnt  = offsets[bkt + 1] - base;

    if (t < RB) hist[t] = 0;
    __syncthreads();

    if (cnt <= CAP) {
        // ---- pass 1: per-row histogram from ebuf (keys only) ----
        const int* ekey = (const int*)ebuf;
        for (int i = t; i < cnt; i += 256) {
            atomicAdd(&hist[(ekey[2 * (base + i)] >> 16) & (RB - 1)], 1);
        }
        __syncthreads();

        // ---- exclusive scan over RB rows (lanes 0..RB-1 of wave 0) ----
        if (t < RB) {
            const int v = hist[t];
            int s = v;
#pragma unroll
            for (int off = 1; off < RB; off <<= 1) {
                const int u = __shfl_up(s, off);
                if (t >= off) s += u;
            }
            rowoff[t + 1] = s;
            hist[t] = s - v;            // exclusive prefix -> sort cursor
            if (t == 0) rowoff[0] = 0;
        }
        __syncthreads();

        // ---- pass 2: counting sort global -> LDS ----
        for (int i = t; i < cnt; i += 256) {
            const int2 rec = ebuf[base + i];
            const int pos = atomicAdd(&hist[(rec.x >> 16) & (RB - 1)], 1);
            srec[pos] = rec;
        }
        __syncthreads();

        // ---- per-row register accumulation (8 rows per wave) ----
        for (int rr = 0; rr < RB / 4; ++rr) {
            const int row = wave * (RB / 4) + rr;
            const int beg = rowoff[row];
            const int end = rowoff[row + 1];
            float2 acc0 = make_float2(0.f, 0.f);
            float2 acc1 = make_float2(0.f, 0.f);

            int e = beg;
            for (; e + 4 <= end; e += 4) {
                const int2 r0 = srec[e + 0];
                const int2 r1 = srec[e + 1];
                const int2 r2 = srec[e + 2];
                const int2 r3 = srec[e + 3];
                const float2 m0 = __half22float2(((const __half2*)(h + (size_t)(r0.x & 0xFFFF) * OUT_DIM))[lane]);
                const float2 m1 = __half22float2(((const __half2*)(h + (size_t)(r1.x & 0xFFFF) * OUT_DIM))[lane]);
                const float2 m2 = __half22float2(((const __half2*)(h + (size_t)(r2.x & 0xFFFF) * OUT_DIM))[lane]);
                const float2 m3 = __half22float2(((const __half2*)(h + (size_t)(r3.x & 0xFFFF) * OUT_DIM))[lane]);
                const float v0 = __int_as_float(r0.y);
                const float v1 = __int_as_float(r1.y);
                const float v2 = __int_as_float(r2.y);
                const float v3 = __int_as_float(r3.y);
                acc0.x += v0 * m0.x; acc0.y += v0 * m0.y;
                acc1.x += v1 * m1.x; acc1.y += v1 * m1.y;
                acc0.x += v2 * m2.x; acc0.y += v2 * m2.y;
                acc1.x += v3 * m3.x; acc1.y += v3 * m3.y;
            }
            for (; e < end; ++e) {
                const int2 r0 = srec[e];
                const float2 m0 = __half22float2(((const __half2*)(h + (size_t)(r0.x & 0xFFFF) * OUT_DIM))[lane]);
                const float v0 = __int_as_float(r0.y);
                acc0.x += v0 * m0.x; acc0.y += v0 * m0.y;
            }

            float2 acc = make_float2(acc0.x + acc1.x, acc0.y + acc1.y);
            const int grow = bkt * RB + row;
            if (grow < N_NODES) {
                acc.x = acc.x >= 0.f ? acc.x : NEG_SLOPE * acc.x;
                acc.y = acc.y >= 0.f ? acc.y : NEG_SLOPE * acc.y;
                ((float2*)(out + (size_t)grow * OUT_DIM))[lane] = acc;
            }
        }
    } else {
        // ---- overflow fallback (statistically unreachable; correctness net) ----
        for (int rr = 0; rr < RB / 4; ++rr) {
            const int row = wave * (RB / 4) + rr;
            float2 acc = make_float2(0.f, 0.f);
            for (int e = 0; e < cnt; ++e) {
                const int2 rec = ebuf[base + e];
                if (((rec.x >> 16) & (RB - 1)) == row) {
                    const float2 m = __half22float2(((const __half2*)(h + (size_t)(rec.x & 0xFFFF) * OUT_DIM))[lane]);
                    const float v = __int_as_float(rec.y);
                    acc.x += v * m.x; acc.y += v * m.y;
                }
            }
            const int grow = bkt * RB + row;
            if (grow < N_NODES) {
                acc.x = acc.x >= 0.f ? acc.x : NEG_SLOPE * acc.x;
                acc.y = acc.y >= 0.f ? acc.y : NEG_SLOPE * acc.y;
                ((float2*)(out + (size_t)grow * OUT_DIM))[lane] = acc;
            }
        }
    }
}

// ---------------------------------------------------------------------------
// Launch. Order: hist(+W-convert) -> gemm (needs WTL) -> scan -> scatter ->
// gather. Stream is serial; folding W-convert into hist hides it entirely.
// ---------------------------------------------------------------------------
extern "C" void kernel_launch(void* const* d_in, const int* in_sizes, int n_in,
                              void* d_out, int out_size, void* d_ws, size_t ws_size,
                              hipStream_t stream) {
    const float* x    = (const float*)d_in[0];
    const float* w    = (const float*)d_in[1];
    const float* vals = (const float*)d_in[2];
    const int*   rows = (const int*)d_in[3];
    const int*   cols = (const int*)d_in[4];
    float* out = (float*)d_out;

    char* ws = (char*)d_ws;
    size_t off = 0;
    auto alloc = [&](size_t bytes) {
        void* p = ws + off;
        off = (off + bytes + 255) & ~(size_t)255;
        return p;
    };
    __half* h      = (__half*)alloc((size_t)N_NODES * OUT_DIM * sizeof(__half)); // 12.8 MB
    int2*  ebuf    = (int2*) alloc((size_t)N_EDGES * sizeof(int2));              // 12.8 MB
    __half* wtl    = (__half*)alloc((size_t)IN_DIM * OUT_DIM * sizeof(__half));  // 64 KB frag-layout W
    int*   counts  = (int*)  alloc((size_t)NBUCK * sizeof(int));
    int*   offsets = (int*)  alloc((size_t)(NBUCK + 1) * sizeof(int));
    int*   cursor  = (int*)  alloc((size_t)NBUCK * sizeof(int));

    hipMemsetAsync(counts, 0, (size_t)NBUCK * sizeof(int), stream);

    bucket_hist<<<HIST_BLOCKS + CONVW_BLOCKS, 256, 0, stream>>>(rows, counts, w, wtl);
    gemm_xw_mfma<<<GEMM_BLOCKS, 256, 0, stream>>>(x, wtl, h);
    scan_buckets<<<1, 1024, 0, stream>>>(counts, offsets, cursor);
    bucket_scatter<<<SCAT_BLOCKS, 256, 0, stream>>>(rows, cols, vals, cursor, ebuf);
    bucket_gather<<<NBUCK, 256, 0, stream>>>(h, offsets, ebuf, out);
}